// Round 6
// baseline (189.119 us; speedup 1.0000x reference)
//
#include <hip/hip_runtime.h>
#include <hip/hip_bf16.h>
#include <stdint.h>

// MoE experts: E=8, T=2048, H=1024, I=2048, contiguous token groups.
// up = h@w1_e ; up_r = h@w3_e ; gated = silu(up)*up_r ; out = gated@w2_e
// bf16 MFMA compute, fp32 accumulate, weights cvt'd fp32->bf16 on the fly.
//
// Round-6: SPLIT the dual-B gemm1 into gemm2-shaped single-B blocks
// (one 4096-block dispatch, `which` bit selects w1->up or w3->upr), and
// FUSE the silu-gate into the down-GEMM's reg-staged A path. Every GEMM
// block now has the per-phase profile that measured ~0.4 us/phase.
// Pipeline: dist-2 named register sets, lgkm-only barriers, setprio.

#define NE 8
#define NT 2048
#define NH 1024
#define NI 2048

typedef __attribute__((ext_vector_type(8))) short bh8;      // 8 bf16
typedef __attribute__((ext_vector_type(4))) short bh4;      // 4 bf16
typedef __attribute__((ext_vector_type(4))) float f32x4;
typedef __attribute__((ext_vector_type(2))) float f32x2;
typedef __attribute__((ext_vector_type(4))) float float4v;

#define BARRIER() asm volatile("s_waitcnt lgkmcnt(0)\n\ts_barrier" ::: "memory")

static __device__ __forceinline__ unsigned short f2bf(float f) {
  __hip_bfloat16 h = __float2bfloat16(f);   // RNE
  return *reinterpret_cast<unsigned short*>(&h);
}
static __device__ __forceinline__ float bf2f(short s) {
  return __uint_as_float(((unsigned int)(unsigned short)s) << 16);
}

// ---- hiddens fp32 -> bf16 (ws) ----
__global__ __launch_bounds__(256)
void cvt_h_kernel(const float* __restrict__ x, unsigned short* __restrict__ y) {
  int i = blockIdx.x * 256 + threadIdx.x;           // one bh8 per thread
  const float4v* xv = reinterpret_cast<const float4v*>(x);
  float4v a = xv[2 * i], b = xv[2 * i + 1];
  union { bh8 v; unsigned short u[8]; } o;
  o.u[0] = f2bf(a[0]); o.u[1] = f2bf(a[1]); o.u[2] = f2bf(a[2]); o.u[3] = f2bf(a[3]);
  o.u[4] = f2bf(b[0]); o.u[5] = f2bf(b[1]); o.u[6] = f2bf(b[2]); o.u[7] = f2bf(b[3]);
  reinterpret_cast<bh8*>(y)[i] = o.v;
}

// LDS layouts (A and B): [row 128][k 32] bf16, 4 x 16B slots per row,
// slot' = slot ^ ((row>>1)&3). Fragment read = single ds_read_b128.

// ============ UP-GEMM: up = h@w1  /  upr = h@w3 (which-bit) ============
// BM=128 BN=128 BK=32, 8 waves (2x4), dist-2 pipeline, 32 phases.
__global__ __launch_bounds__(512, 2)
void moe_up(const unsigned short* __restrict__ hb,   // [T][H] bf16
            const float* __restrict__ w1,            // [E][H][I]
            const float* __restrict__ w3,            // [E][H][I]
            const int* __restrict__ bsz,
            unsigned short* __restrict__ up,         // [T][I] bf16
            unsigned short* __restrict__ upr) {      // [T][I] bf16
  const int NWG = 4096;            // nt(16) x which(2) x e(8) x mt(16)
  const int wg = (blockIdx.x & 7) * (NWG >> 3) + (blockIdx.x >> 3);
  const int mt = wg & 15;
  const int e = (wg >> 4) & 7;
  const int which = (wg >> 7) & 1;
  const int nt = wg >> 8;

  int off = 0;
#pragma unroll
  for (int j = 0; j < NE; ++j) { int v = bsz[j]; off += (j < e) ? v : 0; }
  const int te = bsz[e];
  if (mt * 128 >= te) return;

  const float* W = which ? w3 : w1;
  unsigned short* O = which ? upr : up;

  const int tid = threadIdx.x;
  const int l = tid & 63, w = tid >> 6;
  const int wr = w >> 2, wc = w & 3;           // wave tile 64m x 32n

  __shared__ __align__(16) unsigned short As[2][128 * 32];
  __shared__ __align__(16) unsigned short Bs[2][128 * 32];

  const int row0 = off + mt * 128;
  const int col0 = nt * 128;

  // A: thread owns row tid>>2, slot tid&3 (bh8 load, swizzled ds_write)
  int gr = row0 + (tid >> 2); if (gr > NT - 1) gr = NT - 1;
  const unsigned short* agA = hb + (size_t)gr * NH + (tid & 3) * 8;
  const int awo = (tid >> 2) * 32 + (((tid & 3) ^ ((tid >> 3) & 3)) * 8);

  // B: lane owns cols 2l, 2l+1; wave w owns k-quad 4w..4w+3.
  const int n0 = 2 * l;
  const float* wp = W + (size_t)e * NH * NI + (size_t)(4 * w) * NI + (col0 + n0);
  const int bwo = n0 * 32 + (((w >> 1) ^ (l & 3)) * 8) + (w & 1) * 4;  // shorts

  const int arow = wr * 64 + (l & 15);
  const int fslA = ((l >> 4) ^ ((l >> 1) & 3)) * 8;
  const int nbase = wc * 32 + (l & 15);
  const int bsl = ((l >> 4) ^ ((nbase >> 1) & 3)) * 8;

  f32x4 acc[4][2] = {};
  bh8 rA0, rA1;
  f32x2 rb0[4], rb1[4];

  auto issue = [&](int t, bh8& rA_, f32x2 (&rb_)[4]) {
    const int k0 = t * 32;
    rA_ = *(const bh8*)(agA + k0);
#pragma unroll
    for (int j = 0; j < 4; ++j) rb_[j] = *(const f32x2*)(wp + (size_t)(k0 + j) * NI);
  };
  auto stage = [&](int b, bh8& rA_, f32x2 (&rb_)[4]) {
    *(bh8*)(&As[b][awo]) = rA_;
    bh4 q0, q1;
#pragma unroll
    for (int j = 0; j < 4; ++j) {
      q0[j] = (short)f2bf(rb_[j][0]); q1[j] = (short)f2bf(rb_[j][1]);
    }
    *(bh4*)(&Bs[b][bwo]) = q0;
    *(bh4*)(&Bs[b][bwo + 32]) = q1;
  };
  auto mfma_step = [&](int b) {
    bh8 af[4];
#pragma unroll
    for (int m = 0; m < 4; ++m)
      af[m] = *(const bh8*)(&As[b][(arow + m * 16) * 32 + fslA]);
    __builtin_amdgcn_s_setprio(1);
#pragma unroll
    for (int nf = 0; nf < 2; ++nf) {
      bh8 bf = *(const bh8*)(&Bs[b][(nbase + nf * 16) * 32 + bsl]);
#pragma unroll
      for (int m = 0; m < 4; ++m)
        acc[m][nf] = __builtin_amdgcn_mfma_f32_16x16x32_bf16(af[m], bf, acc[m][nf], 0, 0, 0);
    }
    __builtin_amdgcn_s_setprio(0);
  };

  issue(0, rA0, rb0);
  issue(1, rA1, rb1);
  stage(0, rA0, rb0);
  BARRIER();

#pragma unroll 1
  for (int u = 0; u < 16; ++u) {
    const int t0 = 2 * u;
    if (t0 + 2 < 32) issue(t0 + 2, rA0, rb0);
    mfma_step(0);
    stage(1, rA1, rb1);
    BARRIER();
    if (t0 + 3 < 32) issue(t0 + 3, rA1, rb1);
    mfma_step(1);
    if (t0 + 2 < 32) stage(0, rA0, rb0);
    BARRIER();
  }

  // epilogue: raw accumulators -> bf16 O, masked by ragged bound
#pragma unroll
  for (int m = 0; m < 4; ++m) {
#pragma unroll
    for (int r = 0; r < 4; ++r) {
      int trow = mt * 128 + wr * 64 + m * 16 + (l >> 4) * 4 + r;
      if (trow < te) {
        size_t base = (size_t)(off + trow) * NI + col0 + wc * 32 + (l & 15);
#pragma unroll
        for (int nf = 0; nf < 2; ++nf)
          O[base + nf * 16] = f2bf(acc[m][nf][r]);
      }
    }
  }
}

// ============ DOWN-GEMM: out = (silu(up)*upr) @ w2, gate fused in A ============
// BM=128 BN=128 BK=32, 8 waves, dist-2 pipeline, 64 phases.
__global__ __launch_bounds__(512, 2)
void moe_down(const unsigned short* __restrict__ up,   // [T][I] bf16
              const unsigned short* __restrict__ upr,  // [T][I] bf16
              const float* __restrict__ w2,            // [E][I][H]
              const int* __restrict__ bsz,
              float* __restrict__ out) {               // [T][H] fp32
  const int NWG = 1024;                        // nt(8) x e(8) x mt(16)
  const int wg = (blockIdx.x & 7) * (NWG >> 3) + (blockIdx.x >> 3);
  const int mt = wg & 15;
  const int e = (wg >> 4) & 7;
  const int nt = wg >> 7;

  int off = 0;
#pragma unroll
  for (int j = 0; j < NE; ++j) { int v = bsz[j]; off += (j < e) ? v : 0; }
  const int te = bsz[e];
  if (mt * 128 >= te) return;

  const int tid = threadIdx.x;
  const int l = tid & 63, w = tid >> 6;
  const int wr = w >> 2, wc = w & 3;

  __shared__ __align__(16) unsigned short As[2][128 * 32];
  __shared__ __align__(16) unsigned short Bs[2][128 * 32];

  const int row0 = off + mt * 128;
  const int col0 = nt * 128;

  int gr = row0 + (tid >> 2); if (gr > NT - 1) gr = NT - 1;
  const size_t aoff = (size_t)gr * NI + (tid & 3) * 8;
  const unsigned short* agU = up + aoff;
  const unsigned short* agR = upr + aoff;
  const int awo = (tid >> 2) * 32 + (((tid & 3) ^ ((tid >> 3) & 3)) * 8);

  const int n0 = 2 * l;
  const float* w2p = w2 + (size_t)e * NI * NH + (size_t)(4 * w) * NH + (col0 + n0);
  const int bwo = n0 * 32 + (((w >> 1) ^ (l & 3)) * 8) + (w & 1) * 4;

  const int arow = wr * 64 + (l & 15);
  const int fslA = ((l >> 4) ^ ((l >> 1) & 3)) * 8;
  const int nbase = wc * 32 + (l & 15);
  const int bsl = ((l >> 4) ^ ((nbase >> 1) & 3)) * 8;

  f32x4 acc[4][2] = {};
  bh8 rU0, rU1, rR0, rR1;
  f32x2 rb0[4], rb1[4];

  auto issue = [&](int t, bh8& rU_, bh8& rR_, f32x2 (&rb_)[4]) {
    const int k0 = t * 32;
    rU_ = *(const bh8*)(agU + k0);
    rR_ = *(const bh8*)(agR + k0);
#pragma unroll
    for (int j = 0; j < 4; ++j) rb_[j] = *(const f32x2*)(w2p + (size_t)(k0 + j) * NH);
  };
  auto stage = [&](int b, bh8& rU_, bh8& rR_, f32x2 (&rb_)[4]) {
    // fused gate: gated = silu(up) * upr, computed in regs
    union { bh8 v; unsigned short u[8]; } ga;
#pragma unroll
    for (int j = 0; j < 8; ++j) {
      float u2 = bf2f(rU_[j]);
      float g = bf2f(rR_[j]);
      ga.u[j] = f2bf((u2 / (1.f + __expf(-u2))) * g);
    }
    *(bh8*)(&As[b][awo]) = ga.v;
    bh4 q0, q1;
#pragma unroll
    for (int j = 0; j < 4; ++j) {
      q0[j] = (short)f2bf(rb_[j][0]); q1[j] = (short)f2bf(rb_[j][1]);
    }
    *(bh4*)(&Bs[b][bwo]) = q0;
    *(bh4*)(&Bs[b][bwo + 32]) = q1;
  };
  auto mfma_step = [&](int b) {
    bh8 af[4];
#pragma unroll
    for (int m = 0; m < 4; ++m)
      af[m] = *(const bh8*)(&As[b][(arow + m * 16) * 32 + fslA]);
    __builtin_amdgcn_s_setprio(1);
#pragma unroll
    for (int nf = 0; nf < 2; ++nf) {
      bh8 bf = *(const bh8*)(&Bs[b][(nbase + nf * 16) * 32 + bsl]);
#pragma unroll
      for (int m = 0; m < 4; ++m)
        acc[m][nf] = __builtin_amdgcn_mfma_f32_16x16x32_bf16(af[m], bf, acc[m][nf], 0, 0, 0);
    }
    __builtin_amdgcn_s_setprio(0);
  };

  issue(0, rU0, rR0, rb0);
  issue(1, rU1, rR1, rb1);
  stage(0, rU0, rR0, rb0);
  BARRIER();

#pragma unroll 1
  for (int u = 0; u < 32; ++u) {
    const int t0 = 2 * u;
    if (t0 + 2 < 64) issue(t0 + 2, rU0, rR0, rb0);
    mfma_step(0);
    stage(1, rU1, rR1, rb1);
    BARRIER();
    if (t0 + 3 < 64) issue(t0 + 3, rU1, rR1, rb1);
    mfma_step(1);
    if (t0 + 2 < 64) stage(0, rU0, rR0, rb0);
    BARRIER();
  }

#pragma unroll
  for (int m = 0; m < 4; ++m) {
#pragma unroll
    for (int r = 0; r < 4; ++r) {
      int trow = mt * 128 + wr * 64 + m * 16 + (l >> 4) * 4 + r;
      if (trow < te) {
        size_t base = (size_t)(off + trow) * NH + col0 + wc * 32 + (l & 15);
#pragma unroll
        for (int nf = 0; nf < 2; ++nf)
          out[base + nf * 16] = acc[m][nf][r];
      }
    }
  }
}

extern "C" void kernel_launch(void* const* d_in, const int* in_sizes, int n_in,
                              void* d_out, int out_size, void* d_ws, size_t ws_size,
                              hipStream_t stream) {
  const float* hiddens = (const float*)d_in[0];
  const float* w1 = (const float*)d_in[1];
  const float* w2 = (const float*)d_in[2];
  const float* w3 = (const float*)d_in[3];
  const int* bsz = (const int*)d_in[4];
  float* out = (float*)d_out;

  // ws: [0,4MB) hiddens bf16 ; [4,12MB) up bf16 ; [12,20MB) upr bf16
  unsigned short* hb = (unsigned short*)d_ws;
  unsigned short* up = hb + (size_t)NT * NH;
  unsigned short* upr = up + (size_t)NT * NI;

  cvt_h_kernel<<<dim3(NT * NH / 8 / 256), dim3(256), 0, stream>>>(hiddens, hb);
  moe_up<<<dim3(4096), dim3(512), 0, stream>>>(hb, w1, w3, bsz, up, upr);
  moe_down<<<dim3(1024), dim3(512), 0, stream>>>(up, upr, w2, bsz, out);
}

// Round 7
// 143.534 us; speedup vs baseline: 1.3176x; 1.3176x over previous
//
#include <hip/hip_runtime.h>
#include <hip/hip_bf16.h>
#include <stdint.h>

// MoE experts: E=8, T=2048, H=1024, I=2048, contiguous token groups.
// up = h@w1_e ; up_r = h@w3_e ; gated = silu(up)*up_r ; out = gated@w2_e
// bf16 MFMA compute, fp32 accumulate, weights cvt'd fp32->bf16 on the fly.
//
// Round-7: gate moved OFF the GEMM critical path. Round-6 fused the silu
// gate into moe_down's per-phase stage() -> 8 fp32 divides + expf on the
// serial inter-barrier path with only ~160 working blocks (1.25/CU, no TLP)
// -> 25us kernel became 122us. Now: standalone memory-bound gate kernel
// (VALU hidden under streaming), moe_down reverted to the round-5 gemm2
// structure that measured ~25us. moe_up unchanged (~64us, next target).

#define NE 8
#define NT 2048
#define NH 1024
#define NI 2048

typedef __attribute__((ext_vector_type(8))) short bh8;      // 8 bf16
typedef __attribute__((ext_vector_type(4))) short bh4;      // 4 bf16
typedef __attribute__((ext_vector_type(4))) float f32x4;
typedef __attribute__((ext_vector_type(2))) float f32x2;
typedef __attribute__((ext_vector_type(4))) float float4v;

#define BARRIER() asm volatile("s_waitcnt lgkmcnt(0)\n\ts_barrier" ::: "memory")

static __device__ __forceinline__ unsigned short f2bf(float f) {
  __hip_bfloat16 h = __float2bfloat16(f);   // RNE
  return *reinterpret_cast<unsigned short*>(&h);
}
static __device__ __forceinline__ float bf2f(short s) {
  return __uint_as_float(((unsigned int)(unsigned short)s) << 16);
}

// ---- hiddens fp32 -> bf16 (ws) ----
__global__ __launch_bounds__(256)
void cvt_h_kernel(const float* __restrict__ x, unsigned short* __restrict__ y) {
  int i = blockIdx.x * 256 + threadIdx.x;           // one bh8 per thread
  const float4v* xv = reinterpret_cast<const float4v*>(x);
  float4v a = xv[2 * i], b = xv[2 * i + 1];
  union { bh8 v; unsigned short u[8]; } o;
  o.u[0] = f2bf(a[0]); o.u[1] = f2bf(a[1]); o.u[2] = f2bf(a[2]); o.u[3] = f2bf(a[3]);
  o.u[4] = f2bf(b[0]); o.u[5] = f2bf(b[1]); o.u[6] = f2bf(b[2]); o.u[7] = f2bf(b[3]);
  reinterpret_cast<bh8*>(y)[i] = o.v;
}

// ---- gate: gated = silu(up) * upr (memory-bound, VALU hidden) ----
__global__ __launch_bounds__(256)
void gate_kernel(const unsigned short* __restrict__ up,
                 const unsigned short* __restrict__ upr,
                 unsigned short* __restrict__ gated) {
  int i = blockIdx.x * 256 + threadIdx.x;           // one bh8 per thread
  bh8 u = reinterpret_cast<const bh8*>(up)[i];
  bh8 g = reinterpret_cast<const bh8*>(upr)[i];
  union { bh8 v; unsigned short s[8]; } o;
#pragma unroll
  for (int j = 0; j < 8; ++j) {
    float uu = bf2f(u[j]);
    float gg = bf2f(g[j]);
    o.s[j] = f2bf((uu / (1.f + __expf(-uu))) * gg);
  }
  reinterpret_cast<bh8*>(gated)[i] = o.v;
}

// LDS layouts (A and B): [row 128][k 32] bf16, 4 x 16B slots per row,
// slot' = slot ^ ((row>>1)&3). Fragment read = single ds_read_b128.

// ============ UP-GEMM: up = h@w1  /  upr = h@w3 (which-bit) ============
// BM=128 BN=128 BK=32, 8 waves (2x4), dist-2 pipeline, 32 phases.
__global__ __launch_bounds__(512, 2)
void moe_up(const unsigned short* __restrict__ hb,   // [T][H] bf16
            const float* __restrict__ w1,            // [E][H][I]
            const float* __restrict__ w3,            // [E][H][I]
            const int* __restrict__ bsz,
            unsigned short* __restrict__ up,         // [T][I] bf16
            unsigned short* __restrict__ upr) {      // [T][I] bf16
  const int NWG = 4096;            // nt(16) x which(2) x e(8) x mt(16)
  const int wg = (blockIdx.x & 7) * (NWG >> 3) + (blockIdx.x >> 3);
  const int mt = wg & 15;
  const int e = (wg >> 4) & 7;
  const int which = (wg >> 7) & 1;
  const int nt = wg >> 8;

  int off = 0;
#pragma unroll
  for (int j = 0; j < NE; ++j) { int v = bsz[j]; off += (j < e) ? v : 0; }
  const int te = bsz[e];
  if (mt * 128 >= te) return;

  const float* W = which ? w3 : w1;
  unsigned short* O = which ? upr : up;

  const int tid = threadIdx.x;
  const int l = tid & 63, w = tid >> 6;
  const int wr = w >> 2, wc = w & 3;           // wave tile 64m x 32n

  __shared__ __align__(16) unsigned short As[2][128 * 32];
  __shared__ __align__(16) unsigned short Bs[2][128 * 32];

  const int row0 = off + mt * 128;
  const int col0 = nt * 128;

  // A: thread owns row tid>>2, slot tid&3 (bh8 load, swizzled ds_write)
  int gr = row0 + (tid >> 2); if (gr > NT - 1) gr = NT - 1;
  const unsigned short* agA = hb + (size_t)gr * NH + (tid & 3) * 8;
  const int awo = (tid >> 2) * 32 + (((tid & 3) ^ ((tid >> 3) & 3)) * 8);

  // B: lane owns cols 2l, 2l+1; wave w owns k-quad 4w..4w+3.
  const int n0 = 2 * l;
  const float* wp = W + (size_t)e * NH * NI + (size_t)(4 * w) * NI + (col0 + n0);
  const int bwo = n0 * 32 + (((w >> 1) ^ (l & 3)) * 8) + (w & 1) * 4;  // shorts

  const int arow = wr * 64 + (l & 15);
  const int fslA = ((l >> 4) ^ ((l >> 1) & 3)) * 8;
  const int nbase = wc * 32 + (l & 15);
  const int bsl = ((l >> 4) ^ ((nbase >> 1) & 3)) * 8;

  f32x4 acc[4][2] = {};
  bh8 rA0, rA1;
  f32x2 rb0[4], rb1[4];

  auto issue = [&](int t, bh8& rA_, f32x2 (&rb_)[4]) {
    const int k0 = t * 32;
    rA_ = *(const bh8*)(agA + k0);
#pragma unroll
    for (int j = 0; j < 4; ++j) rb_[j] = *(const f32x2*)(wp + (size_t)(k0 + j) * NI);
  };
  auto stage = [&](int b, bh8& rA_, f32x2 (&rb_)[4]) {
    *(bh8*)(&As[b][awo]) = rA_;
    bh4 q0, q1;
#pragma unroll
    for (int j = 0; j < 4; ++j) {
      q0[j] = (short)f2bf(rb_[j][0]); q1[j] = (short)f2bf(rb_[j][1]);
    }
    *(bh4*)(&Bs[b][bwo]) = q0;
    *(bh4*)(&Bs[b][bwo + 32]) = q1;
  };
  auto mfma_step = [&](int b) {
    bh8 af[4];
#pragma unroll
    for (int m = 0; m < 4; ++m)
      af[m] = *(const bh8*)(&As[b][(arow + m * 16) * 32 + fslA]);
    __builtin_amdgcn_s_setprio(1);
#pragma unroll
    for (int nf = 0; nf < 2; ++nf) {
      bh8 bf = *(const bh8*)(&Bs[b][(nbase + nf * 16) * 32 + bsl]);
#pragma unroll
      for (int m = 0; m < 4; ++m)
        acc[m][nf] = __builtin_amdgcn_mfma_f32_16x16x32_bf16(af[m], bf, acc[m][nf], 0, 0, 0);
    }
    __builtin_amdgcn_s_setprio(0);
  };

  issue(0, rA0, rb0);
  issue(1, rA1, rb1);
  stage(0, rA0, rb0);
  BARRIER();

#pragma unroll 1
  for (int u = 0; u < 16; ++u) {
    const int t0 = 2 * u;
    if (t0 + 2 < 32) issue(t0 + 2, rA0, rb0);
    mfma_step(0);
    stage(1, rA1, rb1);
    BARRIER();
    if (t0 + 3 < 32) issue(t0 + 3, rA1, rb1);
    mfma_step(1);
    if (t0 + 2 < 32) stage(0, rA0, rb0);
    BARRIER();
  }

  // epilogue: raw accumulators -> bf16 O, masked by ragged bound
#pragma unroll
  for (int m = 0; m < 4; ++m) {
#pragma unroll
    for (int r = 0; r < 4; ++r) {
      int trow = mt * 128 + wr * 64 + m * 16 + (l >> 4) * 4 + r;
      if (trow < te) {
        size_t base = (size_t)(off + trow) * NI + col0 + wc * 32 + (l & 15);
#pragma unroll
        for (int nf = 0; nf < 2; ++nf)
          O[base + nf * 16] = f2bf(acc[m][nf][r]);
      }
    }
  }
}

// ============ DOWN-GEMM: out = gated @ w2 -> fp32 (round-5 structure) ============
// BM=128 BN=128 BK=32, 8 waves, dist-2 pipeline, 64 phases.
__global__ __launch_bounds__(512, 2)
void moe_down(const unsigned short* __restrict__ gated,  // [T][I] bf16
              const float* __restrict__ w2,              // [E][I][H]
              const int* __restrict__ bsz,
              float* __restrict__ out) {                 // [T][H] fp32
  const int NWG = 1024;                        // nt(8) x e(8) x mt(16)
  const int wg = (blockIdx.x & 7) * (NWG >> 3) + (blockIdx.x >> 3);
  const int mt = wg & 15;
  const int e = (wg >> 4) & 7;
  const int nt = wg >> 7;

  int off = 0;
#pragma unroll
  for (int j = 0; j < NE; ++j) { int v = bsz[j]; off += (j < e) ? v : 0; }
  const int te = bsz[e];
  if (mt * 128 >= te) return;

  const int tid = threadIdx.x;
  const int l = tid & 63, w = tid >> 6;
  const int wr = w >> 2, wc = w & 3;

  __shared__ __align__(16) unsigned short As[2][128 * 32];
  __shared__ __align__(16) unsigned short Bs[2][128 * 32];

  const int row0 = off + mt * 128;
  const int col0 = nt * 128;

  int gr = row0 + (tid >> 2); if (gr > NT - 1) gr = NT - 1;
  const unsigned short* agA = gated + (size_t)gr * NI + (tid & 3) * 8;
  const int awo = (tid >> 2) * 32 + (((tid & 3) ^ ((tid >> 3) & 3)) * 8);

  const int n0 = 2 * l;
  const float* w2p = w2 + (size_t)e * NI * NH + (size_t)(4 * w) * NH + (col0 + n0);
  const int bwo = n0 * 32 + (((w >> 1) ^ (l & 3)) * 8) + (w & 1) * 4;

  const int arow = wr * 64 + (l & 15);
  const int fslA = ((l >> 4) ^ ((l >> 1) & 3)) * 8;
  const int nbase = wc * 32 + (l & 15);
  const int bsl = ((l >> 4) ^ ((nbase >> 1) & 3)) * 8;

  f32x4 acc[4][2] = {};
  bh8 rA0, rA1;
  f32x2 rb0[4], rb1[4];

  auto issue = [&](int t, bh8& rA_, f32x2 (&rb_)[4]) {
    const int k0 = t * 32;
    rA_ = *(const bh8*)(agA + k0);
#pragma unroll
    for (int j = 0; j < 4; ++j) rb_[j] = *(const f32x2*)(w2p + (size_t)(k0 + j) * NH);
  };
  auto stage = [&](int b, bh8& rA_, f32x2 (&rb_)[4]) {
    *(bh8*)(&As[b][awo]) = rA_;
    bh4 q0, q1;
#pragma unroll
    for (int j = 0; j < 4; ++j) {
      q0[j] = (short)f2bf(rb_[j][0]); q1[j] = (short)f2bf(rb_[j][1]);
    }
    *(bh4*)(&Bs[b][bwo]) = q0;
    *(bh4*)(&Bs[b][bwo + 32]) = q1;
  };
  auto mfma_step = [&](int b) {
    bh8 af[4];
#pragma unroll
    for (int m = 0; m < 4; ++m)
      af[m] = *(const bh8*)(&As[b][(arow + m * 16) * 32 + fslA]);
    __builtin_amdgcn_s_setprio(1);
#pragma unroll
    for (int nf = 0; nf < 2; ++nf) {
      bh8 bf = *(const bh8*)(&Bs[b][(nbase + nf * 16) * 32 + bsl]);
#pragma unroll
      for (int m = 0; m < 4; ++m)
        acc[m][nf] = __builtin_amdgcn_mfma_f32_16x16x32_bf16(af[m], bf, acc[m][nf], 0, 0, 0);
    }
    __builtin_amdgcn_s_setprio(0);
  };

  issue(0, rA0, rb0);
  issue(1, rA1, rb1);
  stage(0, rA0, rb0);
  BARRIER();

#pragma unroll 1
  for (int u = 0; u < 32; ++u) {
    const int t0 = 2 * u;
    if (t0 + 2 < 64) issue(t0 + 2, rA0, rb0);
    mfma_step(0);
    stage(1, rA1, rb1);
    BARRIER();
    if (t0 + 3 < 64) issue(t0 + 3, rA1, rb1);
    mfma_step(1);
    if (t0 + 2 < 64) stage(0, rA0, rb0);
    BARRIER();
  }

#pragma unroll
  for (int m = 0; m < 4; ++m) {
#pragma unroll
    for (int r = 0; r < 4; ++r) {
      int trow = mt * 128 + wr * 64 + m * 16 + (l >> 4) * 4 + r;
      if (trow < te) {
        size_t base = (size_t)(off + trow) * NH + col0 + wc * 32 + (l & 15);
#pragma unroll
        for (int nf = 0; nf < 2; ++nf)
          out[base + nf * 16] = acc[m][nf][r];
      }
    }
  }
}

extern "C" void kernel_launch(void* const* d_in, const int* in_sizes, int n_in,
                              void* d_out, int out_size, void* d_ws, size_t ws_size,
                              hipStream_t stream) {
  const float* hiddens = (const float*)d_in[0];
  const float* w1 = (const float*)d_in[1];
  const float* w2 = (const float*)d_in[2];
  const float* w3 = (const float*)d_in[3];
  const int* bsz = (const int*)d_in[4];
  float* out = (float*)d_out;

  // ws: [0,4MB) hiddens bf16 ; [4,12MB) up ; [12,20MB) upr ; [20,28MB) gated
  unsigned short* hb = (unsigned short*)d_ws;
  unsigned short* up = hb + (size_t)NT * NH;
  unsigned short* upr = up + (size_t)NT * NI;
  unsigned short* gated = upr + (size_t)NT * NI;

  cvt_h_kernel<<<dim3(NT * NH / 8 / 256), dim3(256), 0, stream>>>(hiddens, hb);
  moe_up<<<dim3(4096), dim3(512), 0, stream>>>(hb, w1, w3, bsz, up, upr);
  gate_kernel<<<dim3(NT * NI / 8 / 256), dim3(256), 0, stream>>>(up, upr, gated);
  moe_down<<<dim3(1024), dim3(512), 0, stream>>>(gated, w2, bsz, out);
}

// Round 8
// 136.413 us; speedup vs baseline: 1.3864x; 1.0522x over previous
//
#include <hip/hip_runtime.h>
#include <hip/hip_bf16.h>
#include <stdint.h>

// MoE experts: E=8, T=2048, H=1024, I=2048, contiguous token groups.
// up = h@w1_e ; up_r = h@w3_e ; gated = silu(up)*up_r ; out = gated@w2_e
// bf16 MFMA compute, fp32 accumulate, weights cvt'd fp32->bf16 on the fly.
//
// Round-8: transplant moe_up into moe_down's measured-good regime.
// Evidence: down (150 blocks, <=1/CU) runs 0.39us/phase @2.8TB/s; up
// (640 blocks, ~2.5/CU) runs 1.35us/phase @1.05TB/s with the same code
// shape. Change: BN 128->256 for up (two-half B staging, acc[4][4],
// LDS 48KB, VGPR ~140 -> 1 block/CU) => ~320 working blocks, denser
// phases (16 MFMA, 9 loads). down/gate/cvt unchanged for attribution.

#define NE 8
#define NT 2048
#define NH 1024
#define NI 2048

typedef __attribute__((ext_vector_type(8))) short bh8;      // 8 bf16
typedef __attribute__((ext_vector_type(4))) short bh4;      // 4 bf16
typedef __attribute__((ext_vector_type(4))) float f32x4;
typedef __attribute__((ext_vector_type(2))) float f32x2;
typedef __attribute__((ext_vector_type(4))) float float4v;

#define BARRIER() asm volatile("s_waitcnt lgkmcnt(0)\n\ts_barrier" ::: "memory")

static __device__ __forceinline__ unsigned short f2bf(float f) {
  __hip_bfloat16 h = __float2bfloat16(f);   // RNE
  return *reinterpret_cast<unsigned short*>(&h);
}
static __device__ __forceinline__ float bf2f(short s) {
  return __uint_as_float(((unsigned int)(unsigned short)s) << 16);
}

// ---- hiddens fp32 -> bf16 (ws) ----
__global__ __launch_bounds__(256)
void cvt_h_kernel(const float* __restrict__ x, unsigned short* __restrict__ y) {
  int i = blockIdx.x * 256 + threadIdx.x;           // one bh8 per thread
  const float4v* xv = reinterpret_cast<const float4v*>(x);
  float4v a = xv[2 * i], b = xv[2 * i + 1];
  union { bh8 v; unsigned short u[8]; } o;
  o.u[0] = f2bf(a[0]); o.u[1] = f2bf(a[1]); o.u[2] = f2bf(a[2]); o.u[3] = f2bf(a[3]);
  o.u[4] = f2bf(b[0]); o.u[5] = f2bf(b[1]); o.u[6] = f2bf(b[2]); o.u[7] = f2bf(b[3]);
  reinterpret_cast<bh8*>(y)[i] = o.v;
}

// ---- gate: gated = silu(up) * upr (memory-bound, VALU hidden) ----
__global__ __launch_bounds__(256)
void gate_kernel(const unsigned short* __restrict__ up,
                 const unsigned short* __restrict__ upr,
                 unsigned short* __restrict__ gated) {
  int i = blockIdx.x * 256 + threadIdx.x;           // one bh8 per thread
  bh8 u = reinterpret_cast<const bh8*>(up)[i];
  bh8 g = reinterpret_cast<const bh8*>(upr)[i];
  union { bh8 v; unsigned short s[8]; } o;
#pragma unroll
  for (int j = 0; j < 8; ++j) {
    float uu = bf2f(u[j]);
    float gg = bf2f(g[j]);
    o.s[j] = f2bf((uu / (1.f + __expf(-uu))) * gg);
  }
  reinterpret_cast<bh8*>(gated)[i] = o.v;
}

// LDS layouts: [row][k 32] bf16, 4 x 16B slots per row,
// slot' = slot ^ ((row>>1)&3). Fragment read = single ds_read_b128.

// ============ UP-GEMM: up = h@w1  /  upr = h@w3 (which-bit) ============
// BM=128 BN=256 BK=32, 8 waves (2x4), dist-2 pipeline, 32 phases.
__global__ __launch_bounds__(512, 2)
void moe_up(const unsigned short* __restrict__ hb,   // [T][H] bf16
            const float* __restrict__ w1,            // [E][H][I]
            const float* __restrict__ w3,            // [E][H][I]
            const int* __restrict__ bsz,
            unsigned short* __restrict__ up,         // [T][I] bf16
            unsigned short* __restrict__ upr) {      // [T][I] bf16
  const int NWG = 2048;            // nt(8) x which(2) x e(8) x mt(16)
  const int wg = (blockIdx.x & 7) * (NWG >> 3) + (blockIdx.x >> 3);
  const int mt = wg & 15;
  const int e = (wg >> 4) & 7;
  const int which = (wg >> 7) & 1;
  const int nt = wg >> 8;                  // 0..7, one nt per XCD chunk

  int off = 0;
#pragma unroll
  for (int j = 0; j < NE; ++j) { int v = bsz[j]; off += (j < e) ? v : 0; }
  const int te = bsz[e];
  if (mt * 128 >= te) return;

  const float* W = which ? w3 : w1;
  unsigned short* O = which ? upr : up;

  const int tid = threadIdx.x;
  const int l = tid & 63, w = tid >> 6;
  const int wr = w >> 2, wc = w & 3;           // wave tile 64m x 64n

  __shared__ __align__(16) unsigned short As[2][128 * 32];   // 2 x 8KB
  __shared__ __align__(16) unsigned short Bs[2][256 * 32];   // 2 x 16KB

  const int row0 = off + mt * 128;
  const int col0 = nt * 256;

  // A: thread owns row tid>>2, slot tid&3 (bh8 load, swizzled ds_write)
  int gr = row0 + (tid >> 2); if (gr > NT - 1) gr = NT - 1;
  const unsigned short* agA = hb + (size_t)gr * NH + (tid & 3) * 8;
  const int awo = (tid >> 2) * 32 + (((tid & 3) ^ ((tid >> 3) & 3)) * 8);

  // B (two 128-col halves, each r7-style): lane covers cols 2l,2l+1 of each
  // half; wave w owns k-quad 4w..4w+3.
  const int n0 = 2 * l;
  const float* wp0 = W + (size_t)e * NH * NI + (size_t)(4 * w) * NI + (col0 + n0);
  const float* wp1 = wp0 + 128;
  const int bwo0 = n0 * 32 + (((w >> 1) ^ (l & 3)) * 8) + (w & 1) * 4;   // shorts
  const int bwo1 = bwo0 + 128 * 32;

  const int arow = wr * 64 + (l & 15);
  const int fslA = ((l >> 4) ^ ((l >> 1) & 3)) * 8;
  const int nbase = wc * 64 + (l & 15);
  const int bsl = ((l >> 4) ^ ((nbase >> 1) & 3)) * 8;  // same for all nf (16|nf·16)

  f32x4 acc[4][4] = {};
  bh8 rA0, rA1;
  f32x2 rb0[8], rb1[8];

  auto issue = [&](int t, bh8& rA_, f32x2 (&rb_)[8]) {
    const int k0 = t * 32;
    rA_ = *(const bh8*)(agA + k0);
#pragma unroll
    for (int j = 0; j < 4; ++j) rb_[j] = *(const f32x2*)(wp0 + (size_t)(k0 + j) * NI);
#pragma unroll
    for (int j = 0; j < 4; ++j) rb_[4 + j] = *(const f32x2*)(wp1 + (size_t)(k0 + j) * NI);
  };
  auto stage = [&](int b, bh8& rA_, f32x2 (&rb_)[8]) {
    *(bh8*)(&As[b][awo]) = rA_;
    bh4 q0, q1, q2, q3;
#pragma unroll
    for (int j = 0; j < 4; ++j) {
      q0[j] = (short)f2bf(rb_[j][0]);     q1[j] = (short)f2bf(rb_[j][1]);
      q2[j] = (short)f2bf(rb_[4 + j][0]); q3[j] = (short)f2bf(rb_[4 + j][1]);
    }
    *(bh4*)(&Bs[b][bwo0]) = q0;
    *(bh4*)(&Bs[b][bwo0 + 32]) = q1;
    *(bh4*)(&Bs[b][bwo1]) = q2;
    *(bh4*)(&Bs[b][bwo1 + 32]) = q3;
  };
  auto mfma_step = [&](int b) {
    bh8 af[4];
#pragma unroll
    for (int m = 0; m < 4; ++m)
      af[m] = *(const bh8*)(&As[b][(arow + m * 16) * 32 + fslA]);
    __builtin_amdgcn_s_setprio(1);
#pragma unroll
    for (int nf = 0; nf < 4; ++nf) {
      bh8 bf = *(const bh8*)(&Bs[b][(nbase + nf * 16) * 32 + bsl]);
#pragma unroll
      for (int m = 0; m < 4; ++m)
        acc[m][nf] = __builtin_amdgcn_mfma_f32_16x16x32_bf16(af[m], bf, acc[m][nf], 0, 0, 0);
    }
    __builtin_amdgcn_s_setprio(0);
  };

  issue(0, rA0, rb0);
  issue(1, rA1, rb1);
  stage(0, rA0, rb0);
  BARRIER();

#pragma unroll 1
  for (int u = 0; u < 16; ++u) {
    const int t0 = 2 * u;
    if (t0 + 2 < 32) issue(t0 + 2, rA0, rb0);
    mfma_step(0);
    stage(1, rA1, rb1);
    BARRIER();
    if (t0 + 3 < 32) issue(t0 + 3, rA1, rb1);
    mfma_step(1);
    if (t0 + 2 < 32) stage(0, rA0, rb0);
    BARRIER();
  }

  // epilogue: raw accumulators -> bf16 O, masked by ragged bound
#pragma unroll
  for (int m = 0; m < 4; ++m) {
#pragma unroll
    for (int r = 0; r < 4; ++r) {
      int trow = mt * 128 + wr * 64 + m * 16 + (l >> 4) * 4 + r;
      if (trow < te) {
        size_t base = (size_t)(off + trow) * NI + col0 + wc * 64 + (l & 15);
#pragma unroll
        for (int nf = 0; nf < 4; ++nf)
          O[base + nf * 16] = f2bf(acc[m][nf][r]);
      }
    }
  }
}

// ============ DOWN-GEMM: out = gated @ w2 -> fp32 (r5 structure, measured ~25us) ============
// BM=128 BN=128 BK=32, 8 waves, dist-2 pipeline, 64 phases.
__global__ __launch_bounds__(512, 2)
void moe_down(const unsigned short* __restrict__ gated,  // [T][I] bf16
              const float* __restrict__ w2,              // [E][I][H]
              const int* __restrict__ bsz,
              float* __restrict__ out) {                 // [T][H] fp32
  const int NWG = 1024;                        // nt(8) x e(8) x mt(16)
  const int wg = (blockIdx.x & 7) * (NWG >> 3) + (blockIdx.x >> 3);
  const int mt = wg & 15;
  const int e = (wg >> 4) & 7;
  const int nt = wg >> 7;

  int off = 0;
#pragma unroll
  for (int j = 0; j < NE; ++j) { int v = bsz[j]; off += (j < e) ? v : 0; }
  const int te = bsz[e];
  if (mt * 128 >= te) return;

  const int tid = threadIdx.x;
  const int l = tid & 63, w = tid >> 6;
  const int wr = w >> 2, wc = w & 3;

  __shared__ __align__(16) unsigned short As[2][128 * 32];
  __shared__ __align__(16) unsigned short Bs[2][128 * 32];

  const int row0 = off + mt * 128;
  const int col0 = nt * 128;

  int gr = row0 + (tid >> 2); if (gr > NT - 1) gr = NT - 1;
  const unsigned short* agA = gated + (size_t)gr * NI + (tid & 3) * 8;
  const int awo = (tid >> 2) * 32 + (((tid & 3) ^ ((tid >> 3) & 3)) * 8);

  const int n0 = 2 * l;
  const float* w2p = w2 + (size_t)e * NI * NH + (size_t)(4 * w) * NH + (col0 + n0);
  const int bwo = n0 * 32 + (((w >> 1) ^ (l & 3)) * 8) + (w & 1) * 4;

  const int arow = wr * 64 + (l & 15);
  const int fslA = ((l >> 4) ^ ((l >> 1) & 3)) * 8;
  const int nbase = wc * 32 + (l & 15);
  const int bsl = ((l >> 4) ^ ((nbase >> 1) & 3)) * 8;

  f32x4 acc[4][2] = {};
  bh8 rA0, rA1;
  f32x2 rb0[4], rb1[4];

  auto issue = [&](int t, bh8& rA_, f32x2 (&rb_)[4]) {
    const int k0 = t * 32;
    rA_ = *(const bh8*)(agA + k0);
#pragma unroll
    for (int j = 0; j < 4; ++j) rb_[j] = *(const f32x2*)(w2p + (size_t)(k0 + j) * NH);
  };
  auto stage = [&](int b, bh8& rA_, f32x2 (&rb_)[4]) {
    *(bh8*)(&As[b][awo]) = rA_;
    bh4 q0, q1;
#pragma unroll
    for (int j = 0; j < 4; ++j) {
      q0[j] = (short)f2bf(rb_[j][0]); q1[j] = (short)f2bf(rb_[j][1]);
    }
    *(bh4*)(&Bs[b][bwo]) = q0;
    *(bh4*)(&Bs[b][bwo + 32]) = q1;
  };
  auto mfma_step = [&](int b) {
    bh8 af[4];
#pragma unroll
    for (int m = 0; m < 4; ++m)
      af[m] = *(const bh8*)(&As[b][(arow + m * 16) * 32 + fslA]);
    __builtin_amdgcn_s_setprio(1);
#pragma unroll
    for (int nf = 0; nf < 2; ++nf) {
      bh8 bf = *(const bh8*)(&Bs[b][(nbase + nf * 16) * 32 + bsl]);
#pragma unroll
      for (int m = 0; m < 4; ++m)
        acc[m][nf] = __builtin_amdgcn_mfma_f32_16x16x32_bf16(af[m], bf, acc[m][nf], 0, 0, 0);
    }
    __builtin_amdgcn_s_setprio(0);
  };

  issue(0, rA0, rb0);
  issue(1, rA1, rb1);
  stage(0, rA0, rb0);
  BARRIER();

#pragma unroll 1
  for (int u = 0; u < 32; ++u) {
    const int t0 = 2 * u;
    if (t0 + 2 < 64) issue(t0 + 2, rA0, rb0);
    mfma_step(0);
    stage(1, rA1, rb1);
    BARRIER();
    if (t0 + 3 < 64) issue(t0 + 3, rA1, rb1);
    mfma_step(1);
    if (t0 + 2 < 64) stage(0, rA0, rb0);
    BARRIER();
  }

#pragma unroll
  for (int m = 0; m < 4; ++m) {
#pragma unroll
    for (int r = 0; r < 4; ++r) {
      int trow = mt * 128 + wr * 64 + m * 16 + (l >> 4) * 4 + r;
      if (trow < te) {
        size_t base = (size_t)(off + trow) * NH + col0 + wc * 32 + (l & 15);
#pragma unroll
        for (int nf = 0; nf < 2; ++nf)
          out[base + nf * 16] = acc[m][nf][r];
      }
    }
  }
}

extern "C" void kernel_launch(void* const* d_in, const int* in_sizes, int n_in,
                              void* d_out, int out_size, void* d_ws, size_t ws_size,
                              hipStream_t stream) {
  const float* hiddens = (const float*)d_in[0];
  const float* w1 = (const float*)d_in[1];
  const float* w2 = (const float*)d_in[2];
  const float* w3 = (const float*)d_in[3];
  const int* bsz = (const int*)d_in[4];
  float* out = (float*)d_out;

  // ws: [0,4MB) hiddens bf16 ; [4,12MB) up ; [12,20MB) upr ; [20,28MB) gated
  unsigned short* hb = (unsigned short*)d_ws;
  unsigned short* up = hb + (size_t)NT * NH;
  unsigned short* upr = up + (size_t)NT * NI;
  unsigned short* gated = upr + (size_t)NT * NI;

  cvt_h_kernel<<<dim3(NT * NH / 8 / 256), dim3(256), 0, stream>>>(hiddens, hb);
  moe_up<<<dim3(2048), dim3(512), 0, stream>>>(hb, w1, w3, bsz, up, upr);
  gate_kernel<<<dim3(NT * NI / 8 / 256), dim3(256), 0, stream>>>(up, upr, gated);
  moe_down<<<dim3(1024), dim3(512), 0, stream>>>(gated, w2, bsz, out);
}